// Round 1
// baseline (169.939 us; speedup 1.0000x reference)
//
#include <hip/hip_runtime.h>

#define T_DIM 512
#define B_DIM 8192
#define GB 16      // batch columns per block
#define NC 32      // time chunks
#define LC 16      // timesteps per chunk  (NC*LC == T_DIM)
#define GAMMA 0.99f

// Phase A: read all inputs once, build per-t affine-scan coefficients in
// registers, per-chunk composites in LDS.
// Scan: 16 threads serially compose 32 chunk-composites per b (affine fns).
// Phase B: replay chunk from registers with corrected carry, accumulate
// critic (= adv^2, since v - vtrace == -adv when rho_thr==c_thr) and
// min(surr1, surr2); block-reduce to per-block partials in d_ws.
__launch_bounds__(512, 4)
__global__ void vtrace_main(const float* __restrict__ prob,
                            const float* __restrict__ aprob,
                            const float* __restrict__ v,
                            const float* __restrict__ nv,
                            const float* __restrict__ rw,
                            const int* __restrict__ act,
                            const int* __restrict__ dnn,
                            float* __restrict__ partials) {
    __shared__ float Sc[NC][GB];
    __shared__ float Mc[NC][GB];
    __shared__ float Cin[NC][GB];
    __shared__ float red[16];

    const int tid = threadIdx.x;
    const int bl  = tid & (GB - 1);
    const int c   = tid >> 4;
    const int b   = blockIdx.x * GB + bl;
    const int t0  = c * LC;

    float rat[LC], mm[LC], pp[LC], ss[LC];
    float S = 0.0f, M = 1.0f;

    const float2* __restrict__ prob2  = (const float2*)prob;
    const float2* __restrict__ aprob2 = (const float2*)aprob;

#pragma unroll
    for (int i = LC - 1; i >= 0; --i) {
        const size_t idx = (size_t)(t0 + i) * B_DIM + b;
        float2 pr = prob2[idx];
        float2 qr = aprob2[idx];
        float vv  = v[idx];
        float nvv = nv[idx];
        float rr  = rw[idx];
        int   a   = act[idx];
        int   d   = dnn[idx];

        float pa    = a ? pr.y : pr.x;
        float qa    = a ? qr.y : qr.x;
        // ratio = exp(logp - logp_act) == (pa/sum_p) / (qa/sum_q)
        float ratio = (pa * (qr.x + qr.y)) / ((pr.x + pr.y) * qa);
        float rho   = fminf(ratio, 1.0f);          // == clipped_c too
        float m     = d ? 0.0f : GAMMA * rho;       // gamma*rho*(1-done)
        float p     = rho * (rr - vv);
        (void)nvv;  // folded into the identity d_t = p_t + m_t*nv_t

        rat[i] = ratio; mm[i] = m; pp[i] = p; ss[i] = vv + p;
        // compose f_t(x) = s + m*x in front of running composite (S,M)
        S = ss[i] + m * S;
        M = m * M;
    }

    Sc[c][bl] = S;
    Mc[c][bl] = M;
    __syncthreads();

    // serial cross-chunk scan (reverse over time), one thread per b
    if (tid < GB) {
        float carry = nv[(size_t)(T_DIM - 1) * B_DIM + blockIdx.x * GB + tid];
        for (int cc = NC - 1; cc >= 0; --cc) {
            Cin[cc][tid] = carry;                    // carry entering chunk cc
            carry = Sc[cc][tid] + Mc[cc][tid] * carry;
        }
    }
    __syncthreads();

    float carry  = Cin[c][bl];
    float critic = 0.0f, msum = 0.0f;
#pragma unroll
    for (int i = LC - 1; i >= 0; --i) {
        float adv = pp[i] + mm[i] * carry;           // == -(v - vtrace)
        carry     = ss[i] + mm[i] * carry;           // vtrace_t
        critic += adv * adv;
        float r_ = rat[i];
        float rc = fminf(fmaxf(r_, 0.8f), 1.2f);     // clip(ratio, 1±0.2)
        msum += fminf(r_ * adv, rc * adv);
    }

    // block reduction: wave64 shuffle then cross-wave via LDS
#pragma unroll
    for (int off = 32; off > 0; off >>= 1) {
        critic += __shfl_down(critic, off, 64);
        msum   += __shfl_down(msum, off, 64);
    }
    const int wave = tid >> 6;
    if ((tid & 63) == 0) { red[wave] = critic; red[8 + wave] = msum; }
    __syncthreads();
    if (tid == 0) {
        float cs = 0.0f, ms = 0.0f;
#pragma unroll
        for (int w = 0; w < 8; ++w) { cs += red[w]; ms += red[8 + w]; }
        partials[blockIdx.x]       = cs;   // critic partial (SoA for finalize)
        partials[512 + blockIdx.x] = ms;   // min-surrogate partial
    }
}

__global__ void vtrace_final(const float* __restrict__ partials,
                             float* __restrict__ out) {
    __shared__ float red[16];
    const int tid = threadIdx.x;  // 512 threads, one per main-block partial
    float cs = partials[tid];
    float ms = partials[512 + tid];
#pragma unroll
    for (int off = 32; off > 0; off >>= 1) {
        cs += __shfl_down(cs, off, 64);
        ms += __shfl_down(ms, off, 64);
    }
    const int wave = tid >> 6;
    if ((tid & 63) == 0) { red[wave] = cs; red[8 + wave] = ms; }
    __syncthreads();
    if (tid == 0) {
        float c = 0.0f, m = 0.0f;
#pragma unroll
        for (int w = 0; w < 8; ++w) { c += red[w]; m += red[8 + w]; }
        const float invN = 1.0f / (float)((size_t)T_DIM * B_DIM); // exact pow2
        // total = actor + critic = -mean(min(surr)) + 0.5*mean(adv^2)
        out[0] = 0.5f * c * invN - m * invN;
    }
}

extern "C" void kernel_launch(void* const* d_in, const int* in_sizes, int n_in,
                              void* d_out, int out_size, void* d_ws, size_t ws_size,
                              hipStream_t stream) {
    const float* prob  = (const float*)d_in[0];
    const float* aprob = (const float*)d_in[1];
    const float* v     = (const float*)d_in[2];
    const float* nv    = (const float*)d_in[3];
    const float* rw    = (const float*)d_in[4];
    const int*   act   = (const int*)d_in[5];
    const int*   dnn   = (const int*)d_in[6];
    float* partials = (float*)d_ws;   // 1024 floats used
    float* out      = (float*)d_out;

    vtrace_main<<<B_DIM / GB, GB * NC, 0, stream>>>(prob, aprob, v, nv, rw,
                                                    act, dnn, partials);
    vtrace_final<<<1, 512, 0, stream>>>(partials, out);
}